// Round 8
// baseline (1629.715 us; speedup 1.0000x reference)
//
#include <hip/hip_runtime.h>
#include <hip/hip_bf16.h>

#define S_LEN   2048
#define D_MODEL 1024
#define N_HEADS 16
#define N_GROUPS 4
#define D_K     64
#define KV_DIM  (N_GROUPS * D_K)   // 256

typedef __hip_bfloat16 bf16;

__device__ __forceinline__ float b2f(unsigned short u) {
    return __uint_as_float(((unsigned)u) << 16);
}

// ---------------- per-input dtype probe (established: all fp32) ----------------
__global__ void probe5_kernel(const unsigned short* __restrict__ p0,
                              const unsigned short* __restrict__ p1,
                              const unsigned short* __restrict__ p2,
                              const unsigned short* __restrict__ p3,
                              const unsigned short* __restrict__ p4,
                              int* __restrict__ mode) {
    if (threadIdx.x == 0 && blockIdx.x == 0) {
        const unsigned short* ps[5] = {p0, p1, p2, p3, p4};
        for (int t = 0; t < 5; t++) {
            int extreme = 0;
            for (int i = 0; i < 128; i++) {
                int e = (ps[t][i] >> 7) & 0xFF;
                if (e < 100 || e > 140) extreme++;
            }
            mode[t] = (extreme > 16) ? 1 : 0;
        }
    }
}

// ---------------- RoPE (fp32 math, fp32 out into d_out scratch) ----------------
__global__ __launch_bounds__(512)
void rope_kernel(const void* __restrict__ Xin, float* __restrict__ Xr,
                 const int* __restrict__ mode) {
    int i = blockIdx.x;
    int j = threadIdx.x;
    int md = mode[0];
    float freq = powf(10000.0f, -(float)j * (1.0f / 512.0f));
    float ang  = (float)i * freq;
    float sv, cv;
    sincosf(ang, &sv, &cv);
    int base = i * D_MODEL;
    float xe, xo;
    if (md) {
        float2 xv = *(const float2*)&((const float*)Xin)[base + 2 * j];
        xe = xv.x; xo = xv.y;
    } else {
        ushort2 xv = *(const ushort2*)&((const unsigned short*)Xin)[base + 2 * j];
        xe = b2f(xv.x); xo = b2f(xv.y);
    }
    Xr[base + j]       = xe * cv - xo * sv;
    Xr[base + 512 + j] = xe * sv + xo * cv;
}

// ---------------- GEMM: C[M,N] = A[M,K] * B[N,K]^T ----------------
// A: fp32 or bf16 (template). B: weights, fp32/bf16 per mode slot. C: bf16 or fp32.
__device__ __forceinline__ void loadA4(const float* p, float* dst) {
    float4 v = *(const float4*)p;
    dst[0] = v.x; dst[1] = v.y; dst[2] = v.z; dst[3] = v.w;
}
__device__ __forceinline__ void loadA4(const bf16* p, float* dst) {
    ushort4 v = *(const ushort4*)p;
    dst[0] = b2f(v.x); dst[1] = b2f(v.y); dst[2] = b2f(v.z); dst[3] = b2f(v.w);
}
__device__ __forceinline__ void storeC(float* p, float v) { *p = v; }
__device__ __forceinline__ void storeC(bf16* p, float v)  { *p = __float2bfloat16(v); }

template <typename AT, typename OT>
__global__ __launch_bounds__(256)
void gemm_nt(const AT* __restrict__ A, const void* __restrict__ B,
             OT* __restrict__ C, int M, int N, int K,
             const int* __restrict__ modeSlot) {
    const int BM = 64, BN = 64, BK = 16;
    __shared__ float As[BK][BM + 4];
    __shared__ float Bs[BK][BN + 4];

    int tid = threadIdx.x;
    int tx = tid & 15;
    int ty = tid >> 4;
    int m0 = blockIdx.y * BM;
    int n0 = blockIdx.x * BN;

    int lr = tid >> 2;
    int lk = (tid & 3) * 4;
    int md = modeSlot[0];

    float acc[4][4] = {};

    for (int k0 = 0; k0 < K; k0 += BK) {
        float av[4];
        loadA4(&A[(size_t)(m0 + lr) * K + k0 + lk], av);
        As[lk + 0][lr] = av[0];
        As[lk + 1][lr] = av[1];
        As[lk + 2][lr] = av[2];
        As[lk + 3][lr] = av[3];
        if (md) {
            float4 bv = *(const float4*)&((const float*)B)[(size_t)(n0 + lr) * K + k0 + lk];
            Bs[lk + 0][lr] = bv.x;
            Bs[lk + 1][lr] = bv.y;
            Bs[lk + 2][lr] = bv.z;
            Bs[lk + 3][lr] = bv.w;
        } else {
            ushort4 bv = *(const ushort4*)&((const unsigned short*)B)[(size_t)(n0 + lr) * K + k0 + lk];
            Bs[lk + 0][lr] = b2f(bv.x);
            Bs[lk + 1][lr] = b2f(bv.y);
            Bs[lk + 2][lr] = b2f(bv.z);
            Bs[lk + 3][lr] = b2f(bv.w);
        }
        __syncthreads();
        #pragma unroll
        for (int kk = 0; kk < BK; kk++) {
            float4 a = *(const float4*)&As[kk][ty * 4];
            float4 b = *(const float4*)&Bs[kk][tx * 4];
            float ar[4] = {a.x, a.y, a.z, a.w};
            float br[4] = {b.x, b.y, b.z, b.w};
            #pragma unroll
            for (int ii = 0; ii < 4; ii++)
                #pragma unroll
                for (int jj = 0; jj < 4; jj++)
                    acc[ii][jj] += ar[ii] * br[jj];
        }
        __syncthreads();
    }

    #pragma unroll
    for (int ii = 0; ii < 4; ii++)
        #pragma unroll
        for (int jj = 0; jj < 4; jj++)
            storeC(&C[(size_t)(m0 + ty * 4 + ii) * N + n0 + tx * 4 + jj], acc[ii][jj]);
}

// ---------------- Attention (flash-style, causal, GQA) ----------------
__global__ __launch_bounds__(256)
void attn_kernel(const bf16* __restrict__ Q, const bf16* __restrict__ K,
                 const bf16* __restrict__ V, bf16* __restrict__ O) {
    int i = blockIdx.x;
    int h = blockIdx.y;
    int g = h >> 2;
    int tid = threadIdx.x;
    int d = tid & 63;
    int part = tid >> 6;

    __shared__ float q_s[64];
    __shared__ float Ks[64][65];
    __shared__ float Vs[64][65];
    __shared__ float sc[64];
    __shared__ float sp[4][64];
    __shared__ float m_sh, l_sh, al_sh;

    if (tid < 64) q_s[tid] = __bfloat162float(Q[(size_t)i * D_MODEL + h * 64 + tid]);
    if (tid == 0) { m_sh = -INFINITY; l_sh = 0.0f; }
    float acc = 0.0f;
    __syncthreads();

    for (int j0 = 0; j0 <= i; j0 += 64) {
        #pragma unroll
        for (int rep = 0; rep < 16; rep++) {
            int idx = rep * 256 + tid;
            int jj = idx >> 6, dd = idx & 63;
            Ks[jj][dd] = __bfloat162float(K[(size_t)(j0 + jj) * KV_DIM + g * 64 + dd]);
            Vs[jj][dd] = __bfloat162float(V[(size_t)(j0 + jj) * KV_DIM + g * 64 + dd]);
        }
        __syncthreads();

        float partial = 0.0f;
        #pragma unroll
        for (int kk = 0; kk < 16; kk++)
            partial += q_s[part * 16 + kk] * Ks[d][part * 16 + kk];
        sp[part][d] = partial;
        __syncthreads();

        if (tid < 64) {
            float sv = (sp[0][tid] + sp[1][tid] + sp[2][tid] + sp[3][tid]) * 0.125f;
            sc[tid] = (j0 + tid <= i) ? sv : -1e30f;
            float v = sc[tid];
            #pragma unroll
            for (int off = 32; off > 0; off >>= 1)
                v = fmaxf(v, __shfl_xor(v, off, 64));
            if (tid == 0) {
                float mn = fmaxf(m_sh, v);
                al_sh = __expf(m_sh - mn);
                m_sh = mn;
            }
        }
        __syncthreads();
        float alpha = al_sh;
        float m = m_sh;
        if (tid < 64) {
            float p = __expf(sc[tid] - m);
            sc[tid] = p;
            float v = p;
            #pragma unroll
            for (int off = 32; off > 0; off >>= 1)
                v += __shfl_xor(v, off, 64);
            if (tid == 0) l_sh = l_sh * alpha + v;
        }
        __syncthreads();

        acc *= alpha;
        #pragma unroll
        for (int jj = 0; jj < 16; jj++)
            acc += sc[part * 16 + jj] * Vs[part * 16 + jj][d];
        __syncthreads();
    }

    sp[part][d] = acc;
    __syncthreads();
    if (tid < 64) {
        float o = (sp[0][tid] + sp[1][tid] + sp[2][tid] + sp[3][tid]) / l_sh;
        O[(size_t)i * D_MODEL + h * 64 + tid] = __float2bfloat16(o);
    }
}

extern "C" void kernel_launch(void* const* d_in, const int* in_sizes, int n_in,
                              void* d_out, int out_size, void* d_ws, size_t ws_size,
                              hipStream_t stream) {
    const void* X  = d_in[0];
    const void* Wq = d_in[1];
    const void* Wk = d_in[2];
    const void* Wv = d_in[3];
    const void* Wo = d_in[4];
    float* out = (float*)d_out;            // OUTPUT IS FP32 (round-7 probe)

    // ws: mode[5] 64B | Qm 4MB | Km 1MB | Vm 1MB | Om 4MB = 10,485,824 B
    // (proven available in round 4). Xr lives as fp32 in d_out (8MB), consumed
    // by the projection GEMMs before the final GEMM overwrites d_out.
    int*  mode = (int*)d_ws;
    bf16* Qm = (bf16*)((char*)d_ws + 64);
    bf16* Km = Qm + (size_t)S_LEN * D_MODEL;
    bf16* Vm = Km + (size_t)S_LEN * KV_DIM;
    bf16* Om = Vm + (size_t)S_LEN * KV_DIM;
    float* Xr = out;

    probe5_kernel<<<1, 64, 0, stream>>>(
        (const unsigned short*)X,  (const unsigned short*)Wq,
        (const unsigned short*)Wk, (const unsigned short*)Wv,
        (const unsigned short*)Wo, mode);

    rope_kernel<<<S_LEN, 512, 0, stream>>>(X, Xr, mode + 0);

    gemm_nt<float, bf16><<<dim3(D_MODEL / 64, S_LEN / 64), 256, 0, stream>>>(
        Xr, Wq, Qm, S_LEN, D_MODEL, D_MODEL, mode + 1);
    gemm_nt<float, bf16><<<dim3(KV_DIM / 64, S_LEN / 64), 256, 0, stream>>>(
        Xr, Wk, Km, S_LEN, KV_DIM, D_MODEL, mode + 2);
    gemm_nt<float, bf16><<<dim3(KV_DIM / 64, S_LEN / 64), 256, 0, stream>>>(
        Xr, Wv, Vm, S_LEN, KV_DIM, D_MODEL, mode + 3);

    attn_kernel<<<dim3(S_LEN, N_HEADS), 256, 0, stream>>>(Qm, Km, Vm, Om);

    gemm_nt<bf16, float><<<dim3(D_MODEL / 64, S_LEN / 64), 256, 0, stream>>>(
        Om, Wo, out, S_LEN, D_MODEL, D_MODEL, mode + 4);
}

// Round 9
// 425.197 us; speedup vs baseline: 3.8328x; 3.8328x over previous
//
#include <hip/hip_runtime.h>
#include <hip/hip_bf16.h>

#define S_LEN   2048
#define D_MODEL 1024
#define N_HEADS 16
#define N_GROUPS 4
#define D_K     64
#define KV_DIM  (N_GROUPS * D_K)   // 256

typedef __hip_bfloat16 bf16;
typedef __attribute__((ext_vector_type(8))) short bfrag;   // 8 bf16 = 4 VGPR
typedef __attribute__((ext_vector_type(4))) float ffrag;   // 4 fp32 acc

__device__ __forceinline__ float b2f(unsigned short u) {
    return __uint_as_float(((unsigned)u) << 16);
}
__device__ __forceinline__ unsigned short f2bu(float f) {
    __hip_bfloat16 h = __float2bfloat16(f);
    return __builtin_bit_cast(unsigned short, h);
}

// ---------------- per-input dtype probe (established: all fp32) ----------------
__global__ void probe5_kernel(const unsigned short* __restrict__ p0,
                              const unsigned short* __restrict__ p1,
                              const unsigned short* __restrict__ p2,
                              const unsigned short* __restrict__ p3,
                              const unsigned short* __restrict__ p4,
                              int* __restrict__ mode) {
    if (threadIdx.x == 0 && blockIdx.x == 0) {
        const unsigned short* ps[5] = {p0, p1, p2, p3, p4};
        for (int t = 0; t < 5; t++) {
            int extreme = 0;
            for (int i = 0; i < 128; i++) {
                int e = (ps[t][i] >> 7) & 0xFF;
                if (e < 100 || e > 140) extreme++;
            }
            mode[t] = (extreme > 16) ? 1 : 0;
        }
    }
}

// ---------------- RoPE (fp32 math, fp32 out into d_out scratch) ----------------
__global__ __launch_bounds__(512)
void rope_kernel(const void* __restrict__ Xin, float* __restrict__ Xr,
                 const int* __restrict__ mode) {
    int i = blockIdx.x;
    int j = threadIdx.x;
    int md = mode[0];
    float freq = powf(10000.0f, -(float)j * (1.0f / 512.0f));
    float ang  = (float)i * freq;
    float sv, cv;
    sincosf(ang, &sv, &cv);
    int base = i * D_MODEL;
    float xe, xo;
    if (md) {
        float2 xv = *(const float2*)&((const float*)Xin)[base + 2 * j];
        xe = xv.x; xo = xv.y;
    } else {
        ushort2 xv = *(const ushort2*)&((const unsigned short*)Xin)[base + 2 * j];
        xe = b2f(xv.x); xo = b2f(xv.y);
    }
    Xr[base + j]       = xe * cv - xo * sv;
    Xr[base + 512 + j] = xe * sv + xo * cv;
}

// ---------------- GEMM: C[M,N] = A[M,K] * B[N,K]^T (VALU, unchanged) ----------------
__device__ __forceinline__ void loadA4(const float* p, float* dst) {
    float4 v = *(const float4*)p;
    dst[0] = v.x; dst[1] = v.y; dst[2] = v.z; dst[3] = v.w;
}
__device__ __forceinline__ void loadA4(const bf16* p, float* dst) {
    ushort4 v = *(const ushort4*)p;
    dst[0] = b2f(v.x); dst[1] = b2f(v.y); dst[2] = b2f(v.z); dst[3] = b2f(v.w);
}
__device__ __forceinline__ void storeC(float* p, float v) { *p = v; }
__device__ __forceinline__ void storeC(bf16* p, float v)  { *p = __float2bfloat16(v); }

template <typename AT, typename OT>
__global__ __launch_bounds__(256)
void gemm_nt(const AT* __restrict__ A, const void* __restrict__ B,
             OT* __restrict__ C, int M, int N, int K,
             const int* __restrict__ modeSlot) {
    const int BM = 64, BN = 64, BK = 16;
    __shared__ float As[BK][BM + 4];
    __shared__ float Bs[BK][BN + 4];

    int tid = threadIdx.x;
    int tx = tid & 15;
    int ty = tid >> 4;
    int m0 = blockIdx.y * BM;
    int n0 = blockIdx.x * BN;

    int lr = tid >> 2;
    int lk = (tid & 3) * 4;
    int md = modeSlot[0];

    float acc[4][4] = {};

    for (int k0 = 0; k0 < K; k0 += BK) {
        float av[4];
        loadA4(&A[(size_t)(m0 + lr) * K + k0 + lk], av);
        As[lk + 0][lr] = av[0];
        As[lk + 1][lr] = av[1];
        As[lk + 2][lr] = av[2];
        As[lk + 3][lr] = av[3];
        if (md) {
            float4 bv = *(const float4*)&((const float*)B)[(size_t)(n0 + lr) * K + k0 + lk];
            Bs[lk + 0][lr] = bv.x;
            Bs[lk + 1][lr] = bv.y;
            Bs[lk + 2][lr] = bv.z;
            Bs[lk + 3][lr] = bv.w;
        } else {
            ushort4 bv = *(const ushort4*)&((const unsigned short*)B)[(size_t)(n0 + lr) * K + k0 + lk];
            Bs[lk + 0][lr] = b2f(bv.x);
            Bs[lk + 1][lr] = b2f(bv.y);
            Bs[lk + 2][lr] = b2f(bv.z);
            Bs[lk + 3][lr] = b2f(bv.w);
        }
        __syncthreads();
        #pragma unroll
        for (int kk = 0; kk < BK; kk++) {
            float4 a = *(const float4*)&As[kk][ty * 4];
            float4 b = *(const float4*)&Bs[kk][tx * 4];
            float ar[4] = {a.x, a.y, a.z, a.w};
            float br[4] = {b.x, b.y, b.z, b.w};
            #pragma unroll
            for (int ii = 0; ii < 4; ii++)
                #pragma unroll
                for (int jj = 0; jj < 4; jj++)
                    acc[ii][jj] += ar[ii] * br[jj];
        }
        __syncthreads();
    }

    #pragma unroll
    for (int ii = 0; ii < 4; ii++)
        #pragma unroll
        for (int jj = 0; jj < 4; jj++)
            storeC(&C[(size_t)(m0 + ty * 4 + ii) * N + n0 + tx * 4 + jj], acc[ii][jj]);
}

// ---------------- MFMA flash attention (causal, GQA) ----------------
// Block = (64-query tile, head). 256 threads = 4 waves, wave w owns rows
// i0+w*16 .. +15. mfma_f32_16x16x32_bf16 for QK^T and PV.
// Layouts (m89/m120 verified): A[m=lane&15][k=quad*8+j], B[n=lane&15][k=quad*8+j],
// C/D col=lane&15, row=quad*4+reg.
__global__ __launch_bounds__(256)
void attn_mfma(const unsigned short* __restrict__ Q, const unsigned short* __restrict__ K,
               const unsigned short* __restrict__ V, unsigned short* __restrict__ O) {
    const int i0 = blockIdx.x * 64;
    const int h  = blockIdx.y;
    const int g  = h >> 2;
    const int tid  = threadIdx.x;
    const int w    = tid >> 6;
    const int lane = tid & 63;
    const int quad = lane >> 4;
    const int lcol = lane & 15;

    __shared__ unsigned short Ks[64][72];      // [key][dim], +8 pad
    __shared__ unsigned short Vs[64][72];      // [dim][key] transposed, +8 pad
    __shared__ unsigned short Ps[4][16][72];   // per-wave P round-trip, +8 pad

    // Q fragments: lane holds Q[row = i0+w*16+lcol][k-chunk], 8 contiguous dims
    const int qrow = i0 + w * 16 + lcol;
    const bfrag qa0 = *(const bfrag*)&Q[qrow * D_MODEL + h * 64 + 0 * 32 + quad * 8];
    const bfrag qa1 = *(const bfrag*)&Q[qrow * D_MODEL + h * 64 + 1 * 32 + quad * 8];

    ffrag oacc[4];
    #pragma unroll
    for (int ct = 0; ct < 4; ct++) oacc[ct] = (ffrag)0.0f;
    float m_run[4], l_run[4];
    #pragma unroll
    for (int r = 0; r < 4; r++) { m_run[r] = -1e30f; l_run[r] = 0.0f; }

    const int nt = (i0 >> 6) + 1;
    for (int t = 0; t < nt; t++) {
        const int j0 = t * 64;

        // ---- stage K [key][dim] and V transposed [dim][key] ----
        #pragma unroll
        for (int rep = 0; rep < 2; rep++) {
            int c = tid + rep * 256;           // 0..511
            int key = c & 63, dc = c >> 6;     // dc: 8-dim chunk 0..7
            const uint4 kv = *(const uint4*)&K[(j0 + key) * KV_DIM + g * 64 + dc * 8];
            *(uint4*)&Ks[key][dc * 8] = kv;
            const uint4 vv = *(const uint4*)&V[(j0 + key) * KV_DIM + g * 64 + dc * 8];
            unsigned int vw0 = vv.x, vw1 = vv.y, vw2 = vv.z, vw3 = vv.w;
            Vs[dc * 8 + 0][key] = (unsigned short)(vw0 & 0xffff);
            Vs[dc * 8 + 1][key] = (unsigned short)(vw0 >> 16);
            Vs[dc * 8 + 2][key] = (unsigned short)(vw1 & 0xffff);
            Vs[dc * 8 + 3][key] = (unsigned short)(vw1 >> 16);
            Vs[dc * 8 + 4][key] = (unsigned short)(vw2 & 0xffff);
            Vs[dc * 8 + 5][key] = (unsigned short)(vw2 >> 16);
            Vs[dc * 8 + 6][key] = (unsigned short)(vw3 & 0xffff);
            Vs[dc * 8 + 7][key] = (unsigned short)(vw3 >> 16);
        }
        __syncthreads();

        // ---- S = Q K^T : 4 col-tiles (16 keys each) x 2 k-chunks ----
        ffrag sacc[4];
        #pragma unroll
        for (int ct = 0; ct < 4; ct++) sacc[ct] = (ffrag)0.0f;
        #pragma unroll
        for (int ct = 0; ct < 4; ct++) {
            const bfrag kb0 = *(const bfrag*)&Ks[ct * 16 + lcol][0 * 32 + quad * 8];
            sacc[ct] = __builtin_amdgcn_mfma_f32_16x16x32_bf16(qa0, kb0, sacc[ct], 0, 0, 0);
            const bfrag kb1 = *(const bfrag*)&Ks[ct * 16 + lcol][1 * 32 + quad * 8];
            sacc[ct] = __builtin_amdgcn_mfma_f32_16x16x32_bf16(qa1, kb1, sacc[ct], 0, 0, 0);
        }

        // ---- scale + causal mask ----
        float s[4][4];
        #pragma unroll
        for (int ct = 0; ct < 4; ct++)
            #pragma unroll
            for (int r = 0; r < 4; r++) {
                int qi = i0 + w * 16 + quad * 4 + r;
                int kj = j0 + ct * 16 + lcol;
                s[ct][r] = (kj <= qi) ? sacc[ct][r] * 0.125f : -1e30f;
            }

        // ---- online softmax (row = quad*4+r, spread over 16 lanes of quad) ----
        float alpha[4], mnew[4];
        #pragma unroll
        for (int r = 0; r < 4; r++) {
            float mx = fmaxf(fmaxf(s[0][r], s[1][r]), fmaxf(s[2][r], s[3][r]));
            #pragma unroll
            for (int off = 1; off < 16; off <<= 1)
                mx = fmaxf(mx, __shfl_xor(mx, off, 64));
            mnew[r] = fmaxf(m_run[r], mx);
            alpha[r] = __expf(m_run[r] - mnew[r]);
            m_run[r] = mnew[r];
        }
        #pragma unroll
        for (int r = 0; r < 4; r++) {
            float rs = 0.0f;
            #pragma unroll
            for (int ct = 0; ct < 4; ct++) {
                float p = __expf(s[ct][r] - mnew[r]);
                s[ct][r] = p;
                rs += p;
            }
            #pragma unroll
            for (int off = 1; off < 16; off <<= 1)
                rs += __shfl_xor(rs, off, 64);
            l_run[r] = l_run[r] * alpha[r] + rs;
        }

        // ---- P: C-layout -> LDS -> A-layout (per-wave, in-order DS ops) ----
        #pragma unroll
        for (int ct = 0; ct < 4; ct++)
            #pragma unroll
            for (int r = 0; r < 4; r++)
                Ps[w][quad * 4 + r][ct * 16 + lcol] = f2bu(s[ct][r]);

        // ---- rescale O ----
        #pragma unroll
        for (int ct = 0; ct < 4; ct++)
            #pragma unroll
            for (int r = 0; r < 4; r++)
                oacc[ct][r] *= alpha[r];

        // ---- O += P V ----
        const bfrag pa0 = *(const bfrag*)&Ps[w][lcol][0 * 32 + quad * 8];
        const bfrag pa1 = *(const bfrag*)&Ps[w][lcol][1 * 32 + quad * 8];
        #pragma unroll
        for (int ct = 0; ct < 4; ct++) {
            const bfrag vb0 = *(const bfrag*)&Vs[ct * 16 + lcol][0 * 32 + quad * 8];
            oacc[ct] = __builtin_amdgcn_mfma_f32_16x16x32_bf16(pa0, vb0, oacc[ct], 0, 0, 0);
            const bfrag vb1 = *(const bfrag*)&Vs[ct * 16 + lcol][1 * 32 + quad * 8];
            oacc[ct] = __builtin_amdgcn_mfma_f32_16x16x32_bf16(pa1, vb1, oacc[ct], 0, 0, 0);
        }
        __syncthreads();
    }

    // ---- normalize + store (C-layout) ----
    #pragma unroll
    for (int ct = 0; ct < 4; ct++)
        #pragma unroll
        for (int r = 0; r < 4; r++) {
            int row = i0 + w * 16 + quad * 4 + r;
            O[row * D_MODEL + h * 64 + ct * 16 + lcol] = f2bu(oacc[ct][r] / l_run[r]);
        }
}

extern "C" void kernel_launch(void* const* d_in, const int* in_sizes, int n_in,
                              void* d_out, int out_size, void* d_ws, size_t ws_size,
                              hipStream_t stream) {
    const void* X  = d_in[0];
    const void* Wq = d_in[1];
    const void* Wk = d_in[2];
    const void* Wv = d_in[3];
    const void* Wo = d_in[4];
    float* out = (float*)d_out;            // fp32 output (round-7 probe)

    // ws: mode[5] 64B | Qm 4MB | Km 1MB | Vm 1MB | Om 4MB = 10,485,824 B.
    // Xr fp32 scratch lives in d_out (8MB), consumed before final GEMM.
    int*  mode = (int*)d_ws;
    bf16* Qm = (bf16*)((char*)d_ws + 64);
    bf16* Km = Qm + (size_t)S_LEN * D_MODEL;
    bf16* Vm = Km + (size_t)S_LEN * KV_DIM;
    bf16* Om = Vm + (size_t)S_LEN * KV_DIM;
    float* Xr = out;

    probe5_kernel<<<1, 64, 0, stream>>>(
        (const unsigned short*)X,  (const unsigned short*)Wq,
        (const unsigned short*)Wk, (const unsigned short*)Wv,
        (const unsigned short*)Wo, mode);

    rope_kernel<<<S_LEN, 512, 0, stream>>>(X, Xr, mode + 0);

    gemm_nt<float, bf16><<<dim3(D_MODEL / 64, S_LEN / 64), 256, 0, stream>>>(
        Xr, Wq, Qm, S_LEN, D_MODEL, D_MODEL, mode + 1);
    gemm_nt<float, bf16><<<dim3(KV_DIM / 64, S_LEN / 64), 256, 0, stream>>>(
        Xr, Wk, Km, S_LEN, KV_DIM, D_MODEL, mode + 2);
    gemm_nt<float, bf16><<<dim3(KV_DIM / 64, S_LEN / 64), 256, 0, stream>>>(
        Xr, Wv, Vm, S_LEN, KV_DIM, D_MODEL, mode + 3);

    attn_mfma<<<dim3(S_LEN / 64, N_HEADS), 256, 0, stream>>>(
        (const unsigned short*)Qm, (const unsigned short*)Km,
        (const unsigned short*)Vm, (unsigned short*)Om);

    gemm_nt<bf16, float><<<dim3(D_MODEL / 64, S_LEN / 64), 256, 0, stream>>>(
        Om, Wo, out, S_LEN, D_MODEL, D_MODEL, mode + 4);
}

// Round 10
// 225.628 us; speedup vs baseline: 7.2230x; 1.8845x over previous
//
#include <hip/hip_runtime.h>
#include <hip/hip_bf16.h>

#define S_LEN   2048
#define D_MODEL 1024
#define N_HEADS 16
#define N_GROUPS 4
#define D_K     64
#define KV_DIM  (N_GROUPS * D_K)   // 256

typedef __hip_bfloat16 bf16;
typedef unsigned short u16;
typedef __attribute__((ext_vector_type(8))) short bfrag;   // 8 bf16 = 4 VGPR
typedef __attribute__((ext_vector_type(4))) float ffrag;   // 4 fp32 acc

__device__ __forceinline__ float b2f(u16 u) {
    return __uint_as_float(((unsigned)u) << 16);
}
__device__ __forceinline__ u16 f2bu(float f) {
    bf16 h = __float2bfloat16(f);
    return __builtin_bit_cast(u16, h);
}

// ---------------- per-input dtype probe (established: all fp32) ----------------
__global__ void probe5_kernel(const u16* __restrict__ p0, const u16* __restrict__ p1,
                              const u16* __restrict__ p2, const u16* __restrict__ p3,
                              const u16* __restrict__ p4, int* __restrict__ mode) {
    if (threadIdx.x == 0 && blockIdx.x == 0) {
        const u16* ps[5] = {p0, p1, p2, p3, p4};
        for (int t = 0; t < 5; t++) {
            int extreme = 0;
            for (int i = 0; i < 128; i++) {
                int e = (ps[t][i] >> 7) & 0xFF;
                if (e < 100 || e > 140) extreme++;
            }
            mode[t] = (extreme > 16) ? 1 : 0;
        }
    }
}

// ---------------- fp32/bf16 -> bf16 convert ----------------
__global__ __launch_bounds__(256)
void cvt_kernel(const void* __restrict__ in, u16* __restrict__ out, int n,
                const int* __restrict__ modeSlot) {
    int i = blockIdx.x * 256 + threadIdx.x;
    if (i < n) {
        float v = modeSlot[0] ? ((const float*)in)[i] : b2f(((const u16*)in)[i]);
        out[i] = f2bu(v);
    }
}

// ---------------- RoPE (fp32 math, bf16 out) ----------------
__global__ __launch_bounds__(512)
void rope_kernel(const void* __restrict__ Xin, u16* __restrict__ Xr,
                 const int* __restrict__ mode) {
    int i = blockIdx.x;
    int j = threadIdx.x;
    int md = mode[0];
    float freq = powf(10000.0f, -(float)j * (1.0f / 512.0f));
    float ang  = (float)i * freq;
    float sv, cv;
    sincosf(ang, &sv, &cv);
    int base = i * D_MODEL;
    float xe, xo;
    if (md) {
        float2 xv = *(const float2*)&((const float*)Xin)[base + 2 * j];
        xe = xv.x; xo = xv.y;
    } else {
        ushort2 xv = *(const ushort2*)&((const u16*)Xin)[base + 2 * j];
        xe = b2f(xv.x); xo = b2f(xv.y);
    }
    Xr[base + j]       = f2bu(xe * cv - xo * sv);
    Xr[base + 512 + j] = f2bu(xe * sv + xo * cv);
}

// ================= MFMA GEMM core (shared body via macro-free inline) =========
// C[M,N] = A[M,K] * B[N,K]^T, A/B bf16, fp32 acc. 128x64 tile, BK=32, 4 waves,
// wave w: rows w*32..+31 (2 row-frags), cols 0..63 (4 col-frags).
// LDS [row][k] stride 36 (+4 pad) -> even bank spread for b128.

// ---------------- fused QKV projection ----------------
// N-space: [0,1024) -> Qm (ldc 1024), [1024,1280) -> Km (ldc 256), [1280,1536) -> Vm.
__global__ __launch_bounds__(256)
void qkv_mfma(const u16* __restrict__ Xr, const u16* __restrict__ WqB,
              const u16* __restrict__ WkB, const u16* __restrict__ WvB,
              u16* __restrict__ Qm, u16* __restrict__ Km, u16* __restrict__ Vm) {
    __shared__ u16 As[128][36];
    __shared__ u16 Bs[64][36];
    const int tid = threadIdx.x;
    const int w = tid >> 6, lane = tid & 63, quad = lane >> 4, lcol = lane & 15;
    const int m0 = blockIdx.y * 128;
    const int n0 = blockIdx.x * 64;

    const u16* Bsrc; int nb;
    if (n0 < 1024)       { Bsrc = WqB; nb = n0; }
    else if (n0 < 1280)  { Bsrc = WkB; nb = n0 - 1024; }
    else                 { Bsrc = WvB; nb = n0 - 1280; }

    ffrag acc[2][4];
    #pragma unroll
    for (int rf = 0; rf < 2; rf++)
        #pragma unroll
        for (int ct = 0; ct < 4; ct++) acc[rf][ct] = (ffrag)0.0f;

    const int arow = tid >> 2, akc = tid & 3;
    for (int k0 = 0; k0 < D_MODEL; k0 += 32) {
        *(uint4*)&As[arow][akc * 8] =
            *(const uint4*)&Xr[(size_t)(m0 + arow) * D_MODEL + k0 + akc * 8];
        *(uint4*)&As[arow + 64][akc * 8] =
            *(const uint4*)&Xr[(size_t)(m0 + arow + 64) * D_MODEL + k0 + akc * 8];
        *(uint4*)&Bs[arow][akc * 8] =
            *(const uint4*)&Bsrc[(size_t)(nb + arow) * D_MODEL + k0 + akc * 8];
        __syncthreads();
        const bfrag a0 = *(const bfrag*)&As[w * 32 + lcol][quad * 8];
        const bfrag a1 = *(const bfrag*)&As[w * 32 + 16 + lcol][quad * 8];
        #pragma unroll
        for (int ct = 0; ct < 4; ct++) {
            const bfrag b = *(const bfrag*)&Bs[ct * 16 + lcol][quad * 8];
            acc[0][ct] = __builtin_amdgcn_mfma_f32_16x16x32_bf16(a0, b, acc[0][ct], 0, 0, 0);
            acc[1][ct] = __builtin_amdgcn_mfma_f32_16x16x32_bf16(a1, b, acc[1][ct], 0, 0, 0);
        }
        __syncthreads();
    }

    u16* Cp; int ldc, nc;
    if (n0 < 1024)      { Cp = Qm; ldc = 1024; nc = n0; }
    else if (n0 < 1280) { Cp = Km; ldc = 256;  nc = n0 - 1024; }
    else                { Cp = Vm; ldc = 256;  nc = n0 - 1280; }
    #pragma unroll
    for (int rf = 0; rf < 2; rf++)
        #pragma unroll
        for (int ct = 0; ct < 4; ct++)
            #pragma unroll
            for (int r = 0; r < 4; r++) {
                int row = m0 + w * 32 + rf * 16 + quad * 4 + r;
                Cp[(size_t)row * ldc + nc + ct * 16 + lcol] = f2bu(acc[rf][ct][r]);
            }
}

// ---------------- O projection: C fp32 = A(bf16) B(bf16)^T ----------------
__global__ __launch_bounds__(256)
void oproj_mfma(const u16* __restrict__ A, const u16* __restrict__ B,
                float* __restrict__ C) {
    __shared__ u16 As[128][36];
    __shared__ u16 Bs[64][36];
    const int tid = threadIdx.x;
    const int w = tid >> 6, lane = tid & 63, quad = lane >> 4, lcol = lane & 15;
    const int m0 = blockIdx.y * 128;
    const int n0 = blockIdx.x * 64;

    ffrag acc[2][4];
    #pragma unroll
    for (int rf = 0; rf < 2; rf++)
        #pragma unroll
        for (int ct = 0; ct < 4; ct++) acc[rf][ct] = (ffrag)0.0f;

    const int arow = tid >> 2, akc = tid & 3;
    for (int k0 = 0; k0 < D_MODEL; k0 += 32) {
        *(uint4*)&As[arow][akc * 8] =
            *(const uint4*)&A[(size_t)(m0 + arow) * D_MODEL + k0 + akc * 8];
        *(uint4*)&As[arow + 64][akc * 8] =
            *(const uint4*)&A[(size_t)(m0 + arow + 64) * D_MODEL + k0 + akc * 8];
        *(uint4*)&Bs[arow][akc * 8] =
            *(const uint4*)&B[(size_t)(n0 + arow) * D_MODEL + k0 + akc * 8];
        __syncthreads();
        const bfrag a0 = *(const bfrag*)&As[w * 32 + lcol][quad * 8];
        const bfrag a1 = *(const bfrag*)&As[w * 32 + 16 + lcol][quad * 8];
        #pragma unroll
        for (int ct = 0; ct < 4; ct++) {
            const bfrag b = *(const bfrag*)&Bs[ct * 16 + lcol][quad * 8];
            acc[0][ct] = __builtin_amdgcn_mfma_f32_16x16x32_bf16(a0, b, acc[0][ct], 0, 0, 0);
            acc[1][ct] = __builtin_amdgcn_mfma_f32_16x16x32_bf16(a1, b, acc[1][ct], 0, 0, 0);
        }
        __syncthreads();
    }

    #pragma unroll
    for (int rf = 0; rf < 2; rf++)
        #pragma unroll
        for (int ct = 0; ct < 4; ct++)
            #pragma unroll
            for (int r = 0; r < 4; r++) {
                int row = m0 + w * 32 + rf * 16 + quad * 4 + r;
                C[(size_t)row * D_MODEL + n0 + ct * 16 + lcol] = acc[rf][ct][r];
            }
}

// ---------------- MFMA flash attention (causal, GQA) — unchanged ----------------
__global__ __launch_bounds__(256)
void attn_mfma(const u16* __restrict__ Q, const u16* __restrict__ K,
               const u16* __restrict__ V, u16* __restrict__ O) {
    const int i0 = blockIdx.x * 64;
    const int h  = blockIdx.y;
    const int g  = h >> 2;
    const int tid  = threadIdx.x;
    const int w    = tid >> 6;
    const int lane = tid & 63;
    const int quad = lane >> 4;
    const int lcol = lane & 15;

    __shared__ u16 Ks[64][72];
    __shared__ u16 Vs[64][72];
    __shared__ u16 Ps[4][16][72];

    const int qrow = i0 + w * 16 + lcol;
    const bfrag qa0 = *(const bfrag*)&Q[qrow * D_MODEL + h * 64 + 0 * 32 + quad * 8];
    const bfrag qa1 = *(const bfrag*)&Q[qrow * D_MODEL + h * 64 + 1 * 32 + quad * 8];

    ffrag oacc[4];
    #pragma unroll
    for (int ct = 0; ct < 4; ct++) oacc[ct] = (ffrag)0.0f;
    float m_run[4], l_run[4];
    #pragma unroll
    for (int r = 0; r < 4; r++) { m_run[r] = -1e30f; l_run[r] = 0.0f; }

    const int nt = (i0 >> 6) + 1;
    for (int t = 0; t < nt; t++) {
        const int j0 = t * 64;

        #pragma unroll
        for (int rep = 0; rep < 2; rep++) {
            int c = tid + rep * 256;
            int key = c & 63, dc = c >> 6;
            const uint4 kv = *(const uint4*)&K[(j0 + key) * KV_DIM + g * 64 + dc * 8];
            *(uint4*)&Ks[key][dc * 8] = kv;
            const uint4 vv = *(const uint4*)&V[(j0 + key) * KV_DIM + g * 64 + dc * 8];
            unsigned int vw0 = vv.x, vw1 = vv.y, vw2 = vv.z, vw3 = vv.w;
            Vs[dc * 8 + 0][key] = (u16)(vw0 & 0xffff);
            Vs[dc * 8 + 1][key] = (u16)(vw0 >> 16);
            Vs[dc * 8 + 2][key] = (u16)(vw1 & 0xffff);
            Vs[dc * 8 + 3][key] = (u16)(vw1 >> 16);
            Vs[dc * 8 + 4][key] = (u16)(vw2 & 0xffff);
            Vs[dc * 8 + 5][key] = (u16)(vw2 >> 16);
            Vs[dc * 8 + 6][key] = (u16)(vw3 & 0xffff);
            Vs[dc * 8 + 7][key] = (u16)(vw3 >> 16);
        }
        __syncthreads();

        ffrag sacc[4];
        #pragma unroll
        for (int ct = 0; ct < 4; ct++) sacc[ct] = (ffrag)0.0f;
        #pragma unroll
        for (int ct = 0; ct < 4; ct++) {
            const bfrag kb0 = *(const bfrag*)&Ks[ct * 16 + lcol][0 * 32 + quad * 8];
            sacc[ct] = __builtin_amdgcn_mfma_f32_16x16x32_bf16(qa0, kb0, sacc[ct], 0, 0, 0);
            const bfrag kb1 = *(const bfrag*)&Ks[ct * 16 + lcol][1 * 32 + quad * 8];
            sacc[ct] = __builtin_amdgcn_mfma_f32_16x16x32_bf16(qa1, kb1, sacc[ct], 0, 0, 0);
        }

        float s[4][4];
        #pragma unroll
        for (int ct = 0; ct < 4; ct++)
            #pragma unroll
            for (int r = 0; r < 4; r++) {
                int qi = i0 + w * 16 + quad * 4 + r;
                int kj = j0 + ct * 16 + lcol;
                s[ct][r] = (kj <= qi) ? sacc[ct][r] * 0.125f : -1e30f;
            }

        float alpha[4], mnew[4];
        #pragma unroll
        for (int r = 0; r < 4; r++) {
            float mx = fmaxf(fmaxf(s[0][r], s[1][r]), fmaxf(s[2][r], s[3][r]));
            #pragma unroll
            for (int off = 1; off < 16; off <<= 1)
                mx = fmaxf(mx, __shfl_xor(mx, off, 64));
            mnew[r] = fmaxf(m_run[r], mx);
            alpha[r] = __expf(m_run[r] - mnew[r]);
            m_run[r] = mnew[r];
        }
        #pragma unroll
        for (int r = 0; r < 4; r++) {
            float rs = 0.0f;
            #pragma unroll
            for (int ct = 0; ct < 4; ct++) {
                float p = __expf(s[ct][r] - mnew[r]);
                s[ct][r] = p;
                rs += p;
            }
            #pragma unroll
            for (int off = 1; off < 16; off <<= 1)
                rs += __shfl_xor(rs, off, 64);
            l_run[r] = l_run[r] * alpha[r] + rs;
        }

        #pragma unroll
        for (int ct = 0; ct < 4; ct++)
            #pragma unroll
            for (int r = 0; r < 4; r++)
                Ps[w][quad * 4 + r][ct * 16 + lcol] = f2bu(s[ct][r]);

        #pragma unroll
        for (int ct = 0; ct < 4; ct++)
            #pragma unroll
            for (int r = 0; r < 4; r++)
                oacc[ct][r] *= alpha[r];

        const bfrag pa0 = *(const bfrag*)&Ps[w][lcol][0 * 32 + quad * 8];
        const bfrag pa1 = *(const bfrag*)&Ps[w][lcol][1 * 32 + quad * 8];
        #pragma unroll
        for (int ct = 0; ct < 4; ct++) {
            const bfrag vb0 = *(const bfrag*)&Vs[ct * 16 + lcol][0 * 32 + quad * 8];
            oacc[ct] = __builtin_amdgcn_mfma_f32_16x16x32_bf16(pa0, vb0, oacc[ct], 0, 0, 0);
            const bfrag vb1 = *(const bfrag*)&Vs[ct * 16 + lcol][1 * 32 + quad * 8];
            oacc[ct] = __builtin_amdgcn_mfma_f32_16x16x32_bf16(pa1, vb1, oacc[ct], 0, 0, 0);
        }
        __syncthreads();
    }

    #pragma unroll
    for (int ct = 0; ct < 4; ct++)
        #pragma unroll
        for (int r = 0; r < 4; r++) {
            int row = i0 + w * 16 + quad * 4 + r;
            O[row * D_MODEL + h * 64 + ct * 16 + lcol] = f2bu(oacc[ct][r] / l_run[r]);
        }
}

extern "C" void kernel_launch(void* const* d_in, const int* in_sizes, int n_in,
                              void* d_out, int out_size, void* d_ws, size_t ws_size,
                              hipStream_t stream) {
    const void* X  = d_in[0];
    const void* Wq = d_in[1];
    const void* Wk = d_in[2];
    const void* Wv = d_in[3];
    const void* Wo = d_in[4];
    float* out = (float*)d_out;            // fp32 output (round-7 probe)

    // d_out scratch (8MB, dead before final GEMM writes):
    //   XrB 2048*1024 u16 (4MB) | WqB 1M u16 (2MB) | WkB 256K (0.5MB) | WvB 256K (0.5MB)
    u16* XrB = (u16*)d_out;
    u16* WqB = XrB + (size_t)S_LEN * D_MODEL;
    u16* WkB = WqB + (size_t)D_MODEL * D_MODEL;
    u16* WvB = WkB + (size_t)KV_DIM * D_MODEL;

    // ws (<=10,485,824 B proven): mode 64B | Qm 4MB | Km 1MB | Vm 1MB | Om 4MB.
    // WoB (2MB) reuses Qm slot AFTER attention has consumed Qm.
    int* mode = (int*)d_ws;
    u16* Qm = (u16*)((char*)d_ws + 64);
    u16* Km = Qm + (size_t)S_LEN * D_MODEL;
    u16* Vm = Km + (size_t)S_LEN * KV_DIM;
    u16* Om = Vm + (size_t)S_LEN * KV_DIM;
    u16* WoB = Qm;

    probe5_kernel<<<1, 64, 0, stream>>>(
        (const u16*)X, (const u16*)Wq, (const u16*)Wk, (const u16*)Wv,
        (const u16*)Wo, mode);

    rope_kernel<<<S_LEN, 512, 0, stream>>>(X, XrB, mode + 0);

    cvt_kernel<<<(D_MODEL * D_MODEL) / 256, 256, 0, stream>>>(Wq, WqB, D_MODEL * D_MODEL, mode + 1);
    cvt_kernel<<<(KV_DIM * D_MODEL) / 256, 256, 0, stream>>>(Wk, WkB, KV_DIM * D_MODEL, mode + 2);
    cvt_kernel<<<(KV_DIM * D_MODEL) / 256, 256, 0, stream>>>(Wv, WvB, KV_DIM * D_MODEL, mode + 3);

    qkv_mfma<<<dim3((D_MODEL + 2 * KV_DIM) / 64, S_LEN / 128), 256, 0, stream>>>(
        XrB, WqB, WkB, WvB, Qm, Km, Vm);

    attn_mfma<<<dim3(S_LEN / 64, N_HEADS), 256, 0, stream>>>(Qm, Km, Vm, Om);

    cvt_kernel<<<(D_MODEL * D_MODEL) / 256, 256, 0, stream>>>(Wo, WoB, D_MODEL * D_MODEL, mode + 4);

    oproj_mfma<<<dim3(D_MODEL / 64, S_LEN / 128), 256, 0, stream>>>(Om, WoB, out);
}

// Round 11
// 198.263 us; speedup vs baseline: 8.2200x; 1.1380x over previous
//
#include <hip/hip_runtime.h>
#include <hip/hip_bf16.h>

#define S_LEN   2048
#define D_MODEL 1024
#define N_HEADS 16
#define N_GROUPS 4
#define D_K     64
#define KV_DIM  (N_GROUPS * D_K)   // 256

typedef __hip_bfloat16 bf16;
typedef unsigned short u16;
typedef __attribute__((ext_vector_type(8))) short bfrag;   // 8 bf16 = 4 VGPR
typedef __attribute__((ext_vector_type(4))) float ffrag;   // 4 fp32 acc

__device__ __forceinline__ float b2f(u16 u) {
    return __uint_as_float(((unsigned)u) << 16);
}
__device__ __forceinline__ u16 f2bu(float f) {
    bf16 h = __float2bfloat16(f);
    return __builtin_bit_cast(u16, h);
}

// ---------------- per-input dtype probe (established: all fp32) ----------------
__global__ void probe5_kernel(const u16* __restrict__ p0, const u16* __restrict__ p1,
                              const u16* __restrict__ p2, const u16* __restrict__ p3,
                              const u16* __restrict__ p4, int* __restrict__ mode) {
    if (threadIdx.x == 0 && blockIdx.x == 0) {
        const u16* ps[5] = {p0, p1, p2, p3, p4};
        for (int t = 0; t < 5; t++) {
            int extreme = 0;
            for (int i = 0; i < 128; i++) {
                int e = (ps[t][i] >> 7) & 0xFF;
                if (e < 100 || e > 140) extreme++;
            }
            mode[t] = (extreme > 16) ? 1 : 0;
        }
    }
}

// ---------------- RoPE (fp32 math, bf16 out) ----------------
__global__ __launch_bounds__(512)
void rope_kernel(const void* __restrict__ Xin, u16* __restrict__ Xr,
                 const int* __restrict__ mode) {
    int i = blockIdx.x;
    int j = threadIdx.x;
    int md = mode[0];
    float freq = powf(10000.0f, -(float)j * (1.0f / 512.0f));
    float ang  = (float)i * freq;
    float sv, cv;
    sincosf(ang, &sv, &cv);
    int base = i * D_MODEL;
    float xe, xo;
    if (md) {
        float2 xv = *(const float2*)&((const float*)Xin)[base + 2 * j];
        xe = xv.x; xo = xv.y;
    } else {
        ushort2 xv = *(const ushort2*)&((const u16*)Xin)[base + 2 * j];
        xe = b2f(xv.x); xo = b2f(xv.y);
    }
    Xr[base + j]       = f2bu(xe * cv - xo * sv);
    Xr[base + 512 + j] = f2bu(xe * sv + xo * cv);
}

// ---- helper: stage one 64x32 B-panel row-chunk from fp32/bf16 weights ----
__device__ __forceinline__ void stageB(u16* dst, const void* Bv, size_t off, int md) {
    if (md) {
        const float* Bf = (const float*)Bv;
        float4 b0 = *(const float4*)&Bf[off];
        float4 b1 = *(const float4*)&Bf[off + 4];
        u16 t[8] = {f2bu(b0.x), f2bu(b0.y), f2bu(b0.z), f2bu(b0.w),
                    f2bu(b1.x), f2bu(b1.y), f2bu(b1.z), f2bu(b1.w)};
        *(uint4*)dst = *(const uint4*)t;
    } else {
        *(uint4*)dst = *(const uint4*)&((const u16*)Bv)[off];
    }
}

// ---------------- fused QKV projection (MFMA, B converted in-staging) ----------
// N-space: [0,1024) -> Qm (ldc 1024), [1024,1280) -> Km (ldc 256), [1280,1536) -> Vm.
__global__ __launch_bounds__(256)
void qkv_mfma(const u16* __restrict__ Xr, const void* __restrict__ Wq,
              const void* __restrict__ Wk, const void* __restrict__ Wv,
              u16* __restrict__ Qm, u16* __restrict__ Km, u16* __restrict__ Vm,
              const int* __restrict__ mode) {
    __shared__ u16 As[128][36];
    __shared__ u16 Bs[64][36];
    const int tid = threadIdx.x;
    const int w = tid >> 6, lane = tid & 63, quad = lane >> 4, lcol = lane & 15;
    const int m0 = blockIdx.y * 128;
    const int n0 = blockIdx.x * 64;

    const void* Bv; int nb, md;
    if (n0 < 1024)       { Bv = Wq; nb = n0;        md = mode[1]; }
    else if (n0 < 1280)  { Bv = Wk; nb = n0 - 1024; md = mode[2]; }
    else                 { Bv = Wv; nb = n0 - 1280; md = mode[3]; }

    ffrag acc[2][4];
    #pragma unroll
    for (int rf = 0; rf < 2; rf++)
        #pragma unroll
        for (int ct = 0; ct < 4; ct++) acc[rf][ct] = (ffrag)0.0f;

    const int arow = tid >> 2, akc = tid & 3;
    for (int k0 = 0; k0 < D_MODEL; k0 += 32) {
        *(uint4*)&As[arow][akc * 8] =
            *(const uint4*)&Xr[(size_t)(m0 + arow) * D_MODEL + k0 + akc * 8];
        *(uint4*)&As[arow + 64][akc * 8] =
            *(const uint4*)&Xr[(size_t)(m0 + arow + 64) * D_MODEL + k0 + akc * 8];
        stageB(&Bs[arow][akc * 8], Bv, (size_t)(nb + arow) * D_MODEL + k0 + akc * 8, md);
        __syncthreads();
        const bfrag a0 = *(const bfrag*)&As[w * 32 + lcol][quad * 8];
        const bfrag a1 = *(const bfrag*)&As[w * 32 + 16 + lcol][quad * 8];
        #pragma unroll
        for (int ct = 0; ct < 4; ct++) {
            const bfrag b = *(const bfrag*)&Bs[ct * 16 + lcol][quad * 8];
            acc[0][ct] = __builtin_amdgcn_mfma_f32_16x16x32_bf16(a0, b, acc[0][ct], 0, 0, 0);
            acc[1][ct] = __builtin_amdgcn_mfma_f32_16x16x32_bf16(a1, b, acc[1][ct], 0, 0, 0);
        }
        __syncthreads();
    }

    u16* Cp; int ldc, nc;
    if (n0 < 1024)      { Cp = Qm; ldc = 1024; nc = n0; }
    else if (n0 < 1280) { Cp = Km; ldc = 256;  nc = n0 - 1024; }
    else                { Cp = Vm; ldc = 256;  nc = n0 - 1280; }
    #pragma unroll
    for (int rf = 0; rf < 2; rf++)
        #pragma unroll
        for (int ct = 0; ct < 4; ct++)
            #pragma unroll
            for (int r = 0; r < 4; r++) {
                int row = m0 + w * 32 + rf * 16 + quad * 4 + r;
                Cp[(size_t)row * ldc + nc + ct * 16 + lcol] = f2bu(acc[rf][ct][r]);
            }
}

// ---------------- O projection: C fp32 = A(bf16) B(fp32->bf16)^T ----------------
__global__ __launch_bounds__(256)
void oproj_mfma(const u16* __restrict__ A, const void* __restrict__ B,
                float* __restrict__ C, const int* __restrict__ mode) {
    __shared__ u16 As[128][36];
    __shared__ u16 Bs[64][36];
    const int tid = threadIdx.x;
    const int w = tid >> 6, lane = tid & 63, quad = lane >> 4, lcol = lane & 15;
    const int m0 = blockIdx.y * 128;
    const int n0 = blockIdx.x * 64;
    const int md = mode[4];

    ffrag acc[2][4];
    #pragma unroll
    for (int rf = 0; rf < 2; rf++)
        #pragma unroll
        for (int ct = 0; ct < 4; ct++) acc[rf][ct] = (ffrag)0.0f;

    const int arow = tid >> 2, akc = tid & 3;
    for (int k0 = 0; k0 < D_MODEL; k0 += 32) {
        *(uint4*)&As[arow][akc * 8] =
            *(const uint4*)&A[(size_t)(m0 + arow) * D_MODEL + k0 + akc * 8];
        *(uint4*)&As[arow + 64][akc * 8] =
            *(const uint4*)&A[(size_t)(m0 + arow + 64) * D_MODEL + k0 + akc * 8];
        stageB(&Bs[arow][akc * 8], B, (size_t)(n0 + arow) * D_MODEL + k0 + akc * 8, md);
        __syncthreads();
        const bfrag a0 = *(const bfrag*)&As[w * 32 + lcol][quad * 8];
        const bfrag a1 = *(const bfrag*)&As[w * 32 + 16 + lcol][quad * 8];
        #pragma unroll
        for (int ct = 0; ct < 4; ct++) {
            const bfrag b = *(const bfrag*)&Bs[ct * 16 + lcol][quad * 8];
            acc[0][ct] = __builtin_amdgcn_mfma_f32_16x16x32_bf16(a0, b, acc[0][ct], 0, 0, 0);
            acc[1][ct] = __builtin_amdgcn_mfma_f32_16x16x32_bf16(a1, b, acc[1][ct], 0, 0, 0);
        }
        __syncthreads();
    }

    #pragma unroll
    for (int rf = 0; rf < 2; rf++)
        #pragma unroll
        for (int ct = 0; ct < 4; ct++)
            #pragma unroll
            for (int r = 0; r < 4; r++) {
                int row = m0 + w * 32 + rf * 16 + quad * 4 + r;
                C[(size_t)row * D_MODEL + n0 + ct * 16 + lcol] = acc[rf][ct][r];
            }
}

// ---------------- MFMA flash attention (causal, GQA) ----------------
// 1D grid, longest-first: tile = 31 - bid/16, head = bid%16.
// Register-prefetch of next K/V tile overlaps global latency with compute.
__global__ __launch_bounds__(256)
void attn_mfma(const u16* __restrict__ Q, const u16* __restrict__ K,
               const u16* __restrict__ V, u16* __restrict__ O) {
    const int bid = blockIdx.x;
    const int i0 = (31 - (bid >> 4)) * 64;     // longest blocks dispatch first
    const int h  = bid & 15;
    const int g  = h >> 2;
    const int tid  = threadIdx.x;
    const int w    = tid >> 6;
    const int lane = tid & 63;
    const int quad = lane >> 4;
    const int lcol = lane & 15;

    __shared__ u16 Ks[64][72];
    __shared__ u16 Vs[64][72];
    __shared__ u16 Ps[4][16][72];

    const int qrow = i0 + w * 16 + lcol;
    const bfrag qa0 = *(const bfrag*)&Q[qrow * D_MODEL + h * 64 + 0 * 32 + quad * 8];
    const bfrag qa1 = *(const bfrag*)&Q[qrow * D_MODEL + h * 64 + 1 * 32 + quad * 8];

    ffrag oacc[4];
    #pragma unroll
    for (int ct = 0; ct < 4; ct++) oacc[ct] = (ffrag)0.0f;
    float m_run[4], l_run[4];
    #pragma unroll
    for (int r = 0; r < 4; r++) { m_run[r] = -1e30f; l_run[r] = 0.0f; }

    const int key0 = tid & 63, dc0 = tid >> 6;           // rep 0
    const int key1 = (tid + 256) & 63, dc1 = (tid + 256) >> 6;  // rep 1

    // prefetch tile 0
    uint4 kpre0 = *(const uint4*)&K[key0 * KV_DIM + g * 64 + dc0 * 8];
    uint4 vpre0 = *(const uint4*)&V[key0 * KV_DIM + g * 64 + dc0 * 8];
    uint4 kpre1 = *(const uint4*)&K[key1 * KV_DIM + g * 64 + dc1 * 8];
    uint4 vpre1 = *(const uint4*)&V[key1 * KV_DIM + g * 64 + dc1 * 8];

    const int nt = (i0 >> 6) + 1;
    for (int t = 0; t < nt; t++) {
        const int j0 = t * 64;

        // ---- store prefetched K [key][dim] and V transposed [dim][key] ----
        *(uint4*)&Ks[key0][dc0 * 8] = kpre0;
        *(uint4*)&Ks[key1][dc1 * 8] = kpre1;
        {
            unsigned int w0 = vpre0.x, w1 = vpre0.y, w2 = vpre0.z, w3 = vpre0.w;
            Vs[dc0 * 8 + 0][key0] = (u16)(w0 & 0xffff);
            Vs[dc0 * 8 + 1][key0] = (u16)(w0 >> 16);
            Vs[dc0 * 8 + 2][key0] = (u16)(w1 & 0xffff);
            Vs[dc0 * 8 + 3][key0] = (u16)(w1 >> 16);
            Vs[dc0 * 8 + 4][key0] = (u16)(w2 & 0xffff);
            Vs[dc0 * 8 + 5][key0] = (u16)(w2 >> 16);
            Vs[dc0 * 8 + 6][key0] = (u16)(w3 & 0xffff);
            Vs[dc0 * 8 + 7][key0] = (u16)(w3 >> 16);
            w0 = vpre1.x; w1 = vpre1.y; w2 = vpre1.z; w3 = vpre1.w;
            Vs[dc1 * 8 + 0][key1] = (u16)(w0 & 0xffff);
            Vs[dc1 * 8 + 1][key1] = (u16)(w0 >> 16);
            Vs[dc1 * 8 + 2][key1] = (u16)(w1 & 0xffff);
            Vs[dc1 * 8 + 3][key1] = (u16)(w1 >> 16);
            Vs[dc1 * 8 + 4][key1] = (u16)(w2 & 0xffff);
            Vs[dc1 * 8 + 5][key1] = (u16)(w2 >> 16);
            Vs[dc1 * 8 + 6][key1] = (u16)(w3 & 0xffff);
            Vs[dc1 * 8 + 7][key1] = (u16)(w3 >> 16);
        }
        __syncthreads();

        // ---- issue next tile's global loads (overlap with compute below) ----
        if (t + 1 < nt) {
            const int j0n = (t + 1) * 64;
            kpre0 = *(const uint4*)&K[(j0n + key0) * KV_DIM + g * 64 + dc0 * 8];
            vpre0 = *(const uint4*)&V[(j0n + key0) * KV_DIM + g * 64 + dc0 * 8];
            kpre1 = *(const uint4*)&K[(j0n + key1) * KV_DIM + g * 64 + dc1 * 8];
            vpre1 = *(const uint4*)&V[(j0n + key1) * KV_DIM + g * 64 + dc1 * 8];
        }

        // ---- S = Q K^T ----
        ffrag sacc[4];
        #pragma unroll
        for (int ct = 0; ct < 4; ct++) sacc[ct] = (ffrag)0.0f;
        #pragma unroll
        for (int ct = 0; ct < 4; ct++) {
            const bfrag kb0 = *(const bfrag*)&Ks[ct * 16 + lcol][0 * 32 + quad * 8];
            sacc[ct] = __builtin_amdgcn_mfma_f32_16x16x32_bf16(qa0, kb0, sacc[ct], 0, 0, 0);
            const bfrag kb1 = *(const bfrag*)&Ks[ct * 16 + lcol][1 * 32 + quad * 8];
            sacc[ct] = __builtin_amdgcn_mfma_f32_16x16x32_bf16(qa1, kb1, sacc[ct], 0, 0, 0);
        }

        // ---- scale + causal mask ----
        float s[4][4];
        #pragma unroll
        for (int ct = 0; ct < 4; ct++)
            #pragma unroll
            for (int r = 0; r < 4; r++) {
                int qi = i0 + w * 16 + quad * 4 + r;
                int kj = j0 + ct * 16 + lcol;
                s[ct][r] = (kj <= qi) ? sacc[ct][r] * 0.125f : -1e30f;
            }

        // ---- online softmax ----
        float alpha[4], mnew[4];
        #pragma unroll
        for (int r = 0; r < 4; r++) {
            float mx = fmaxf(fmaxf(s[0][r], s[1][r]), fmaxf(s[2][r], s[3][r]));
            #pragma unroll
            for (int off = 1; off < 16; off <<= 1)
                mx = fmaxf(mx, __shfl_xor(mx, off, 64));
            mnew[r] = fmaxf(m_run[r], mx);
            alpha[r] = __expf(m_run[r] - mnew[r]);
            m_run[r] = mnew[r];
        }
        #pragma unroll
        for (int r = 0; r < 4; r++) {
            float rs = 0.0f;
            #pragma unroll
            for (int ct = 0; ct < 4; ct++) {
                float p = __expf(s[ct][r] - mnew[r]);
                s[ct][r] = p;
                rs += p;
            }
            #pragma unroll
            for (int off = 1; off < 16; off <<= 1)
                rs += __shfl_xor(rs, off, 64);
            l_run[r] = l_run[r] * alpha[r] + rs;
        }

        // ---- P: C-layout -> LDS -> A-layout (per-wave) ----
        #pragma unroll
        for (int ct = 0; ct < 4; ct++)
            #pragma unroll
            for (int r = 0; r < 4; r++)
                Ps[w][quad * 4 + r][ct * 16 + lcol] = f2bu(s[ct][r]);

        #pragma unroll
        for (int ct = 0; ct < 4; ct++)
            #pragma unroll
            for (int r = 0; r < 4; r++)
                oacc[ct][r] *= alpha[r];

        const bfrag pa0 = *(const bfrag*)&Ps[w][lcol][0 * 32 + quad * 8];
        const bfrag pa1 = *(const bfrag*)&Ps[w][lcol][1 * 32 + quad * 8];
        #pragma unroll
        for (int ct = 0; ct < 4; ct++) {
            const bfrag vb0 = *(const bfrag*)&Vs[ct * 16 + lcol][0 * 32 + quad * 8];
            oacc[ct] = __builtin_amdgcn_mfma_f32_16x16x32_bf16(pa0, vb0, oacc[ct], 0, 0, 0);
            const bfrag vb1 = *(const bfrag*)&Vs[ct * 16 + lcol][1 * 32 + quad * 8];
            oacc[ct] = __builtin_amdgcn_mfma_f32_16x16x32_bf16(pa1, vb1, oacc[ct], 0, 0, 0);
        }
        __syncthreads();
    }

    #pragma unroll
    for (int ct = 0; ct < 4; ct++)
        #pragma unroll
        for (int r = 0; r < 4; r++) {
            int row = i0 + w * 16 + quad * 4 + r;
            O[row * D_MODEL + h * 64 + ct * 16 + lcol] = f2bu(oacc[ct][r] / l_run[r]);
        }
}

extern "C" void kernel_launch(void* const* d_in, const int* in_sizes, int n_in,
                              void* d_out, int out_size, void* d_ws, size_t ws_size,
                              hipStream_t stream) {
    const void* X  = d_in[0];
    const void* Wq = d_in[1];
    const void* Wk = d_in[2];
    const void* Wv = d_in[3];
    const void* Wo = d_in[4];
    float* out = (float*)d_out;            // fp32 output (round-7 probe)

    // d_out scratch: XrB bf16 (4MB), dead after qkv_mfma; oproj overwrites d_out.
    u16* XrB = (u16*)d_out;

    // ws (<=10,485,824 B proven): mode 64B | Qm 4MB | Km 1MB | Vm 1MB | Om 4MB.
    int* mode = (int*)d_ws;
    u16* Qm = (u16*)((char*)d_ws + 64);
    u16* Km = Qm + (size_t)S_LEN * D_MODEL;
    u16* Vm = Km + (size_t)S_LEN * KV_DIM;
    u16* Om = Vm + (size_t)S_LEN * KV_DIM;

    probe5_kernel<<<1, 64, 0, stream>>>(
        (const u16*)X, (const u16*)Wq, (const u16*)Wk, (const u16*)Wv,
        (const u16*)Wo, mode);

    rope_kernel<<<S_LEN, 512, 0, stream>>>(X, XrB, mode + 0);

    qkv_mfma<<<dim3((D_MODEL + 2 * KV_DIM) / 64, S_LEN / 128), 256, 0, stream>>>(
        XrB, Wq, Wk, Wv, Qm, Km, Vm, mode);

    attn_mfma<<<(S_LEN / 64) * N_HEADS, 256, 0, stream>>>(Qm, Km, Vm, Om);

    oproj_mfma<<<dim3(D_MODEL / 64, S_LEN / 128), 256, 0, stream>>>(Om, Wo, out, mode);
}

// Round 12
// 194.315 us; speedup vs baseline: 8.3870x; 1.0203x over previous
//
#include <hip/hip_runtime.h>
#include <hip/hip_bf16.h>

#define S_LEN   2048
#define D_MODEL 1024
#define N_HEADS 16
#define N_GROUPS 4
#define D_K     64
#define KV_DIM  (N_GROUPS * D_K)   // 256

typedef __hip_bfloat16 bf16;
typedef unsigned short u16;
typedef __attribute__((ext_vector_type(8))) short bfrag;   // 8 bf16 = 4 VGPR
typedef __attribute__((ext_vector_type(4))) float ffrag;   // 4 fp32 acc

__device__ __forceinline__ float b2f(u16 u) {
    return __uint_as_float(((unsigned)u) << 16);
}
__device__ __forceinline__ u16 f2bu(float f) {
    bf16 h = __float2bfloat16(f);
    return __builtin_bit_cast(u16, h);
}

// ---------------- per-input dtype probe (established: all fp32) ----------------
__global__ void probe5_kernel(const u16* __restrict__ p0, const u16* __restrict__ p1,
                              const u16* __restrict__ p2, const u16* __restrict__ p3,
                              const u16* __restrict__ p4, int* __restrict__ mode) {
    if (threadIdx.x == 0 && blockIdx.x == 0) {
        const u16* ps[5] = {p0, p1, p2, p3, p4};
        for (int t = 0; t < 5; t++) {
            int extreme = 0;
            for (int i = 0; i < 128; i++) {
                int e = (ps[t][i] >> 7) & 0xFF;
                if (e < 100 || e > 140) extreme++;
            }
            mode[t] = (extreme > 16) ? 1 : 0;
        }
    }
}

// ---------------- RoPE (fp32 math, bf16 out) ----------------
__global__ __launch_bounds__(512)
void rope_kernel(const void* __restrict__ Xin, u16* __restrict__ Xr,
                 const int* __restrict__ mode) {
    int i = blockIdx.x;
    int j = threadIdx.x;
    int md = mode[0];
    float freq = powf(10000.0f, -(float)j * (1.0f / 512.0f));
    float ang  = (float)i * freq;
    float sv, cv;
    sincosf(ang, &sv, &cv);
    int base = i * D_MODEL;
    float xe, xo;
    if (md) {
        float2 xv = *(const float2*)&((const float*)Xin)[base + 2 * j];
        xe = xv.x; xo = xv.y;
    } else {
        ushort2 xv = *(const ushort2*)&((const u16*)Xin)[base + 2 * j];
        xe = b2f(xv.x); xo = b2f(xv.y);
    }
    Xr[base + j]       = f2bu(xe * cv - xo * sv);
    Xr[base + 512 + j] = f2bu(xe * sv + xo * cv);
}

// ---- helper: stage one B-panel row-chunk from fp32/bf16 weights ----
__device__ __forceinline__ void stageB(u16* dst, const void* Bv, size_t off, int md) {
    if (md) {
        const float* Bf = (const float*)Bv;
        float4 b0 = *(const float4*)&Bf[off];
        float4 b1 = *(const float4*)&Bf[off + 4];
        u16 t[8] = {f2bu(b0.x), f2bu(b0.y), f2bu(b0.z), f2bu(b0.w),
                    f2bu(b1.x), f2bu(b1.y), f2bu(b1.z), f2bu(b1.w)};
        *(uint4*)dst = *(const uint4*)t;
    } else {
        *(uint4*)dst = *(const uint4*)&((const u16*)Bv)[off];
    }
}

// ---------------- fused QKV projection (MFMA) ----------
__global__ __launch_bounds__(256)
void qkv_mfma(const u16* __restrict__ Xr, const void* __restrict__ Wq,
              const void* __restrict__ Wk, const void* __restrict__ Wv,
              u16* __restrict__ Qm, u16* __restrict__ Km, u16* __restrict__ Vm,
              const int* __restrict__ mode) {
    __shared__ u16 As[128][36];
    __shared__ u16 Bs[64][36];
    const int tid = threadIdx.x;
    const int w = tid >> 6, lane = tid & 63, quad = lane >> 4, lcol = lane & 15;
    const int m0 = blockIdx.y * 128;
    const int n0 = blockIdx.x * 64;

    const void* Bv; int nb, md;
    if (n0 < 1024)       { Bv = Wq; nb = n0;        md = mode[1]; }
    else if (n0 < 1280)  { Bv = Wk; nb = n0 - 1024; md = mode[2]; }
    else                 { Bv = Wv; nb = n0 - 1280; md = mode[3]; }

    ffrag acc[2][4];
    #pragma unroll
    for (int rf = 0; rf < 2; rf++)
        #pragma unroll
        for (int ct = 0; ct < 4; ct++) acc[rf][ct] = (ffrag)0.0f;

    const int arow = tid >> 2, akc = tid & 3;
    for (int k0 = 0; k0 < D_MODEL; k0 += 32) {
        *(uint4*)&As[arow][akc * 8] =
            *(const uint4*)&Xr[(size_t)(m0 + arow) * D_MODEL + k0 + akc * 8];
        *(uint4*)&As[arow + 64][akc * 8] =
            *(const uint4*)&Xr[(size_t)(m0 + arow + 64) * D_MODEL + k0 + akc * 8];
        stageB(&Bs[arow][akc * 8], Bv, (size_t)(nb + arow) * D_MODEL + k0 + akc * 8, md);
        __syncthreads();
        const bfrag a0 = *(const bfrag*)&As[w * 32 + lcol][quad * 8];
        const bfrag a1 = *(const bfrag*)&As[w * 32 + 16 + lcol][quad * 8];
        #pragma unroll
        for (int ct = 0; ct < 4; ct++) {
            const bfrag b = *(const bfrag*)&Bs[ct * 16 + lcol][quad * 8];
            acc[0][ct] = __builtin_amdgcn_mfma_f32_16x16x32_bf16(a0, b, acc[0][ct], 0, 0, 0);
            acc[1][ct] = __builtin_amdgcn_mfma_f32_16x16x32_bf16(a1, b, acc[1][ct], 0, 0, 0);
        }
        __syncthreads();
    }

    u16* Cp; int ldc, nc;
    if (n0 < 1024)      { Cp = Qm; ldc = 1024; nc = n0; }
    else if (n0 < 1280) { Cp = Km; ldc = 256;  nc = n0 - 1024; }
    else                { Cp = Vm; ldc = 256;  nc = n0 - 1280; }
    #pragma unroll
    for (int rf = 0; rf < 2; rf++)
        #pragma unroll
        for (int ct = 0; ct < 4; ct++)
            #pragma unroll
            for (int r = 0; r < 4; r++) {
                int row = m0 + w * 32 + rf * 16 + quad * 4 + r;
                Cp[(size_t)row * ldc + nc + ct * 16 + lcol] = f2bu(acc[rf][ct][r]);
            }
}

// ---------------- O projection: C fp32 = A(bf16) B^T ----------------
__global__ __launch_bounds__(256)
void oproj_mfma(const u16* __restrict__ A, const void* __restrict__ B,
                float* __restrict__ C, const int* __restrict__ mode) {
    __shared__ u16 As[128][36];
    __shared__ u16 Bs[64][36];
    const int tid = threadIdx.x;
    const int w = tid >> 6, lane = tid & 63, quad = lane >> 4, lcol = lane & 15;
    const int m0 = blockIdx.y * 128;
    const int n0 = blockIdx.x * 64;
    const int md = mode[4];

    ffrag acc[2][4];
    #pragma unroll
    for (int rf = 0; rf < 2; rf++)
        #pragma unroll
        for (int ct = 0; ct < 4; ct++) acc[rf][ct] = (ffrag)0.0f;

    const int arow = tid >> 2, akc = tid & 3;
    for (int k0 = 0; k0 < D_MODEL; k0 += 32) {
        *(uint4*)&As[arow][akc * 8] =
            *(const uint4*)&A[(size_t)(m0 + arow) * D_MODEL + k0 + akc * 8];
        *(uint4*)&As[arow + 64][akc * 8] =
            *(const uint4*)&A[(size_t)(m0 + arow + 64) * D_MODEL + k0 + akc * 8];
        stageB(&Bs[arow][akc * 8], B, (size_t)(n0 + arow) * D_MODEL + k0 + akc * 8, md);
        __syncthreads();
        const bfrag a0 = *(const bfrag*)&As[w * 32 + lcol][quad * 8];
        const bfrag a1 = *(const bfrag*)&As[w * 32 + 16 + lcol][quad * 8];
        #pragma unroll
        for (int ct = 0; ct < 4; ct++) {
            const bfrag b = *(const bfrag*)&Bs[ct * 16 + lcol][quad * 8];
            acc[0][ct] = __builtin_amdgcn_mfma_f32_16x16x32_bf16(a0, b, acc[0][ct], 0, 0, 0);
            acc[1][ct] = __builtin_amdgcn_mfma_f32_16x16x32_bf16(a1, b, acc[1][ct], 0, 0, 0);
        }
        __syncthreads();
    }

    #pragma unroll
    for (int rf = 0; rf < 2; rf++)
        #pragma unroll
        for (int ct = 0; ct < 4; ct++)
            #pragma unroll
            for (int r = 0; r < 4; r++) {
                int row = m0 + w * 32 + rf * 16 + quad * 4 + r;
                C[(size_t)row * D_MODEL + n0 + ct * 16 + lcol] = acc[rf][ct][r];
            }
}

// ---------------- split-K MFMA flash attention partials ----------------
// CS: log2(key-tiles per chunk). SF: 1 = fp32 partials (OpF), 0 = bf16 (OpH).
// Block bid: cidx = bid>>4 (query-tile i, chunk c via prefix mapping), head = bid&15.
template<int CS, int SF>
__global__ __launch_bounds__(256)
void attn_part(const u16* __restrict__ Q, const u16* __restrict__ K,
               const u16* __restrict__ V, float* __restrict__ OpF,
               u16* __restrict__ OpH, float2* __restrict__ ml2) {
    const int bid = blockIdx.x;
    const int cidx = bid >> 4;
    const int h = bid & 15;
    const int g = h >> 2;

    int i, c;
    if (CS == 3) {
        if (cidx < 8)       { i = cidx;                  c = 0; }
        else if (cidx < 24) { i = 8 + ((cidx - 8) >> 1); c = (cidx - 8) & 1; }
        else if (cidx < 48) { int q = (cidx - 24) / 3;   i = 16 + q; c = (cidx - 24) - 3 * q; }
        else                { i = 24 + ((cidx - 48) >> 2); c = (cidx - 48) & 3; }
    } else {
        if (cidx < 16) { i = cidx; c = 0; }
        else           { i = 16 + ((cidx - 16) >> 1); c = (cidx - 16) & 1; }
    }
    const int i0 = i * 64;
    const int tile0 = c << CS;
    const int tlast = min(i, ((c + 1) << CS) - 1);
    const int nt = tlast - tile0 + 1;

    const int tid  = threadIdx.x;
    const int w    = tid >> 6;
    const int lane = tid & 63;
    const int quad = lane >> 4;
    const int lcol = lane & 15;

    __shared__ u16 Ks[64][72];
    __shared__ u16 Vs[64][72];
    __shared__ u16 Ps[4][16][72];

    const int qrow = i0 + w * 16 + lcol;
    const bfrag qa0 = *(const bfrag*)&Q[qrow * D_MODEL + h * 64 + 0 * 32 + quad * 8];
    const bfrag qa1 = *(const bfrag*)&Q[qrow * D_MODEL + h * 64 + 1 * 32 + quad * 8];

    ffrag oacc[4];
    #pragma unroll
    for (int ct = 0; ct < 4; ct++) oacc[ct] = (ffrag)0.0f;
    float m_run[4], l_run[4];
    #pragma unroll
    for (int r = 0; r < 4; r++) { m_run[r] = -1e30f; l_run[r] = 0.0f; }

    const int key0 = tid & 63, dc0 = tid >> 6;
    const int key1 = (tid + 256) & 63, dc1 = (tid + 256) >> 6;

    // prefetch first tile of this chunk
    int jp = tile0 * 64;
    uint4 kpre0 = *(const uint4*)&K[(jp + key0) * KV_DIM + g * 64 + dc0 * 8];
    uint4 vpre0 = *(const uint4*)&V[(jp + key0) * KV_DIM + g * 64 + dc0 * 8];
    uint4 kpre1 = *(const uint4*)&K[(jp + key1) * KV_DIM + g * 64 + dc1 * 8];
    uint4 vpre1 = *(const uint4*)&V[(jp + key1) * KV_DIM + g * 64 + dc1 * 8];

    for (int tt = 0; tt < nt; tt++) {
        const int j0 = (tile0 + tt) * 64;

        *(uint4*)&Ks[key0][dc0 * 8] = kpre0;
        *(uint4*)&Ks[key1][dc1 * 8] = kpre1;
        {
            unsigned int w0 = vpre0.x, w1 = vpre0.y, w2 = vpre0.z, w3 = vpre0.w;
            Vs[dc0 * 8 + 0][key0] = (u16)(w0 & 0xffff);
            Vs[dc0 * 8 + 1][key0] = (u16)(w0 >> 16);
            Vs[dc0 * 8 + 2][key0] = (u16)(w1 & 0xffff);
            Vs[dc0 * 8 + 3][key0] = (u16)(w1 >> 16);
            Vs[dc0 * 8 + 4][key0] = (u16)(w2 & 0xffff);
            Vs[dc0 * 8 + 5][key0] = (u16)(w2 >> 16);
            Vs[dc0 * 8 + 6][key0] = (u16)(w3 & 0xffff);
            Vs[dc0 * 8 + 7][key0] = (u16)(w3 >> 16);
            w0 = vpre1.x; w1 = vpre1.y; w2 = vpre1.z; w3 = vpre1.w;
            Vs[dc1 * 8 + 0][key1] = (u16)(w0 & 0xffff);
            Vs[dc1 * 8 + 1][key1] = (u16)(w0 >> 16);
            Vs[dc1 * 8 + 2][key1] = (u16)(w1 & 0xffff);
            Vs[dc1 * 8 + 3][key1] = (u16)(w1 >> 16);
            Vs[dc1 * 8 + 4][key1] = (u16)(w2 & 0xffff);
            Vs[dc1 * 8 + 5][key1] = (u16)(w2 >> 16);
            Vs[dc1 * 8 + 6][key1] = (u16)(w3 & 0xffff);
            Vs[dc1 * 8 + 7][key1] = (u16)(w3 >> 16);
        }
        __syncthreads();

        if (tt + 1 < nt) {
            const int j0n = (tile0 + tt + 1) * 64;
            kpre0 = *(const uint4*)&K[(j0n + key0) * KV_DIM + g * 64 + dc0 * 8];
            vpre0 = *(const uint4*)&V[(j0n + key0) * KV_DIM + g * 64 + dc0 * 8];
            kpre1 = *(const uint4*)&K[(j0n + key1) * KV_DIM + g * 64 + dc1 * 8];
            vpre1 = *(const uint4*)&V[(j0n + key1) * KV_DIM + g * 64 + dc1 * 8];
        }

        ffrag sacc[4];
        #pragma unroll
        for (int ct = 0; ct < 4; ct++) sacc[ct] = (ffrag)0.0f;
        #pragma unroll
        for (int ct = 0; ct < 4; ct++) {
            const bfrag kb0 = *(const bfrag*)&Ks[ct * 16 + lcol][0 * 32 + quad * 8];
            sacc[ct] = __builtin_amdgcn_mfma_f32_16x16x32_bf16(qa0, kb0, sacc[ct], 0, 0, 0);
            const bfrag kb1 = *(const bfrag*)&Ks[ct * 16 + lcol][1 * 32 + quad * 8];
            sacc[ct] = __builtin_amdgcn_mfma_f32_16x16x32_bf16(qa1, kb1, sacc[ct], 0, 0, 0);
        }

        float s[4][4];
        #pragma unroll
        for (int ct = 0; ct < 4; ct++)
            #pragma unroll
            for (int r = 0; r < 4; r++) {
                int qi = i0 + w * 16 + quad * 4 + r;
                int kj = j0 + ct * 16 + lcol;
                s[ct][r] = (kj <= qi) ? sacc[ct][r] * 0.125f : -1e30f;
            }

        float alpha[4], mnew[4];
        #pragma unroll
        for (int r = 0; r < 4; r++) {
            float mx = fmaxf(fmaxf(s[0][r], s[1][r]), fmaxf(s[2][r], s[3][r]));
            #pragma unroll
            for (int off = 1; off < 16; off <<= 1)
                mx = fmaxf(mx, __shfl_xor(mx, off, 64));
            mnew[r] = fmaxf(m_run[r], mx);
            alpha[r] = __expf(m_run[r] - mnew[r]);
            m_run[r] = mnew[r];
        }
        #pragma unroll
        for (int r = 0; r < 4; r++) {
            float rs = 0.0f;
            #pragma unroll
            for (int ct = 0; ct < 4; ct++) {
                float p = __expf(s[ct][r] - mnew[r]);
                s[ct][r] = p;
                rs += p;
            }
            #pragma unroll
            for (int off = 1; off < 16; off <<= 1)
                rs += __shfl_xor(rs, off, 64);
            l_run[r] = l_run[r] * alpha[r] + rs;
        }

        #pragma unroll
        for (int ct = 0; ct < 4; ct++)
            #pragma unroll
            for (int r = 0; r < 4; r++)
                Ps[w][quad * 4 + r][ct * 16 + lcol] = f2bu(s[ct][r]);

        #pragma unroll
        for (int ct = 0; ct < 4; ct++)
            #pragma unroll
            for (int r = 0; r < 4; r++)
                oacc[ct][r] *= alpha[r];

        const bfrag pa0 = *(const bfrag*)&Ps[w][lcol][0 * 32 + quad * 8];
        const bfrag pa1 = *(const bfrag*)&Ps[w][lcol][1 * 32 + quad * 8];
        #pragma unroll
        for (int ct = 0; ct < 4; ct++) {
            const bfrag vb0 = *(const bfrag*)&Vs[ct * 16 + lcol][0 * 32 + quad * 8];
            oacc[ct] = __builtin_amdgcn_mfma_f32_16x16x32_bf16(pa0, vb0, oacc[ct], 0, 0, 0);
            const bfrag vb1 = *(const bfrag*)&Vs[ct * 16 + lcol][1 * 32 + quad * 8];
            oacc[ct] = __builtin_amdgcn_mfma_f32_16x16x32_bf16(pa1, vb1, oacc[ct], 0, 0, 0);
        }
        __syncthreads();
    }

    // store un-normalized partials + (m,l) per row
    #pragma unroll
    for (int ct = 0; ct < 4; ct++)
        #pragma unroll
        for (int r = 0; r < 4; r++) {
            int row = w * 16 + quad * 4 + r;
            size_t off = (size_t)bid * 4096 + row * 64 + ct * 16 + lcol;
            if (SF) OpF[off] = oacc[ct][r];
            else    OpH[off] = f2bu(oacc[ct][r]);
        }
    if (lcol == 0) {
        #pragma unroll
        for (int r = 0; r < 4; r++)
            ml2[(size_t)bid * 64 + w * 16 + quad * 4 + r] = make_float2(m_run[r], l_run[r]);
    }
}

// ---------------- combine partials -> Om (bf16) ----------------
template<int CS, int SF>
__global__ __launch_bounds__(256)
void attn_combine(const float* __restrict__ OpF, const u16* __restrict__ OpH,
                  const float2* __restrict__ ml2, u16* __restrict__ Om) {
    const int row = blockIdx.x;
    const int i = row >> 6;
    const int r = row & 63;
    const int t = threadIdx.x;
    const int h = t >> 4;
    const int d = (t & 15) * 4;
    const int nc = (i >> CS) + 1;
    int pfx;
    if (CS == 3)
        pfx = (i < 8) ? i : (i < 16) ? 8 + 2 * (i - 8)
            : (i < 24) ? 24 + 3 * (i - 16) : 48 + 4 * (i - 24);
    else
        pfx = (i < 16) ? i : 16 + 2 * (i - 16);

    float M = -1e30f;
    for (int c = 0; c < nc; c++) {
        float2 m = ml2[(size_t)((pfx + c) * 16 + h) * 64 + r];
        M = fmaxf(M, m.x);
    }
    float L = 0.0f;
    float acc[4] = {0.0f, 0.0f, 0.0f, 0.0f};
    for (int c = 0; c < nc; c++) {
        float2 m = ml2[(size_t)((pfx + c) * 16 + h) * 64 + r];
        float wgt = __expf(m.x - M);
        L += m.y * wgt;
        size_t off = (size_t)((pfx + c) * 16 + h) * 4096 + r * 64 + d;
        if (SF) {
            float4 v = *(const float4*)&OpF[off];
            acc[0] += v.x * wgt; acc[1] += v.y * wgt;
            acc[2] += v.z * wgt; acc[3] += v.w * wgt;
        } else {
            ushort4 v = *(const ushort4*)&OpH[off];
            acc[0] += b2f(v.x) * wgt; acc[1] += b2f(v.y) * wgt;
            acc[2] += b2f(v.z) * wgt; acc[3] += b2f(v.w) * wgt;
        }
    }
    float inv = 1.0f / L;
    #pragma unroll
    for (int k = 0; k < 4; k++)
        Om[(size_t)row * D_MODEL + h * 64 + d + k] = f2bu(acc[k] * inv);
}

extern "C" void kernel_launch(void* const* d_in, const int* in_sizes, int n_in,
                              void* d_out, int out_size, void* d_ws, size_t ws_size,
                              hipStream_t stream) {
    const void* X  = d_in[0];
    const void* Wq = d_in[1];
    const void* Wk = d_in[2];
    const void* Wv = d_in[3];
    const void* Wo = d_in[4];
    float* out = (float*)d_out;            // fp32 output (round-7 probe)

    // d_out scratch: XrB bf16 (4MB), dead after qkv_mfma.
    u16* XrB = (u16*)d_out;

    // ws base layout (<=10,485,824 proven): mode 64B | Qm 4MB | Km 1MB | Vm 1MB | Om 4MB.
    int* mode = (int*)d_ws;
    u16* Qm = (u16*)((char*)d_ws + 64);
    u16* Km = Qm + (size_t)S_LEN * D_MODEL;
    u16* Vm = Km + (size_t)S_LEN * KV_DIM;
    u16* Om = Vm + (size_t)S_LEN * KV_DIM;

    probe5_kernel<<<1, 64, 0, stream>>>(
        (const u16*)X, (const u16*)Wq, (const u16*)Wk, (const u16*)Wv,
        (const u16*)Wo, mode);

    rope_kernel<<<S_LEN, 512, 0, stream>>>(X, XrB, mode + 0);

    qkv_mfma<<<dim3((D_MODEL + 2 * KV_DIM) / 64, S_LEN / 128), 256, 0, stream>>>(
        XrB, Wq, Wk, Wv, Qm, Km, Vm, mode);

    // split-K attention: path A (fp32 partials in ws) if ws is big enough,
    // else path B (bf16 partials in d_out — XrB is dead by now).
    const size_t needA = 10485824ULL + 20971520ULL + 655360ULL;  // 32,112,704
    if (ws_size >= needA) {
        float*  OpF = (float*)((char*)d_ws + 10485824);
        float2* ml2 = (float2*)((char*)d_ws + 10485824 + 20971520);
        attn_part<3, 1><<<80 * 16, 256, 0, stream>>>(Qm, Km, Vm, OpF, nullptr, ml2);
        attn_combine<3, 1><<<S_LEN, 256, 0, stream>>>(OpF, nullptr, ml2, Om);
    } else {
        u16*    OpH = (u16*)d_out;
        float2* ml2 = (float2*)((char*)d_out + (size_t)768 * 4096 * 2);
        attn_part<4, 0><<<48 * 16, 256, 0, stream>>>(Qm, Km, Vm, nullptr, OpH, ml2);
        attn_combine<4, 0><<<S_LEN, 256, 0, stream>>>(nullptr, OpH, ml2, Om);
    }

    oproj_mfma<<<dim3(D_MODEL / 64, S_LEN / 128), 256, 0, stream>>>(Om, Wo, out, mode);
}